// Round 1
// baseline (197.254 us; speedup 1.0000x reference)
//
#include <hip/hip_runtime.h>
#include <math.h>

#define H 2048
#define II 768
#define TT 512
#define EE 16
#define BK 128

typedef float f32x4 __attribute__((ext_vector_type(4)));
typedef short s16x8 __attribute__((ext_vector_type(8)));
typedef unsigned short u16;
typedef u16 u16x4 __attribute__((ext_vector_type(4)));
typedef u16 u16x8 __attribute__((ext_vector_type(8)));

__device__ __forceinline__ u16 f2bf(float f) {
  unsigned int u = __float_as_uint(f);
  u += 0x7fffu + ((u >> 16) & 1u);   // round-to-nearest-even
  return (u16)(u >> 16);
}

// ---------------- router: logits, sigmoid, top2, counts ----------------
__global__ void router_kernel(const float* __restrict__ x, const float* __restrict__ gw,
                              int* __restrict__ counts, int* __restrict__ topi,
                              float* __restrict__ topw, int* __restrict__ pos) {
  int t = blockIdx.x;
  int tid = threadIdx.x;
  int wave = tid >> 6, lane = tid & 63;
  __shared__ float logits[EE];
  const float* xt = x + (size_t)t * H;
  for (int e = wave * 4; e < wave * 4 + 4; ++e) {
    const float* ge = gw + (size_t)e * H;
    float p = 0.f;
    for (int h = lane * 4; h < H; h += 64 * 4) {
      f32x4 xv = *(const f32x4*)(xt + h);
      f32x4 gv = *(const f32x4*)(ge + h);
      p += xv[0]*gv[0] + xv[1]*gv[1] + xv[2]*gv[2] + xv[3]*gv[3];
    }
    #pragma unroll
    for (int off = 32; off > 0; off >>= 1) p += __shfl_down(p, off);
    if (lane == 0) logits[e] = p;
  }
  __syncthreads();
  if (tid == 0) {
    float s[EE];
    #pragma unroll
    for (int e = 0; e < EE; ++e) s[e] = 1.f / (1.f + expf(-logits[e]));
    int i0 = 0;
    for (int e = 1; e < EE; ++e) if (s[e] > s[i0]) i0 = e;
    int i1 = -1;
    for (int e = 0; e < EE; ++e) {
      if (e == i0) continue;
      if (i1 < 0 || s[e] > s[i1]) i1 = e;
    }
    float w0 = s[i0], w1v = s[i1];
    float inv = 1.f / (w0 + w1v);
    w0 *= inv; w1v *= inv;
    topi[t*2+0] = i0; topi[t*2+1] = i1;
    topw[t*2+0] = w0; topw[t*2+1] = w1v;
    pos[t*2+0] = atomicAdd(&counts[i0], 1);
    pos[t*2+1] = atomicAdd(&counts[i1], 1);
  }
}

// ---------------- prefix sum over 16 experts ----------------
__global__ void prefix_kernel(const int* __restrict__ counts, int* __restrict__ base) {
  int s = 0;
  for (int e = 0; e < EE; ++e) { base[e] = s; s += counts[e]; }
  base[EE] = s;
}

// ---------------- gather tokens into expert-contiguous bf16 rows ----------------
__global__ void gather_kernel(const float* __restrict__ x, const int* __restrict__ topi,
                              const float* __restrict__ topw, const int* __restrict__ pos,
                              const int* __restrict__ base, u16* __restrict__ Xg,
                              int* __restrict__ tok_of, float* __restrict__ wt_of) {
  int t = blockIdx.x, slot = blockIdx.y;
  int e = topi[t*2 + slot];
  int row = base[e] + pos[t*2 + slot];
  if (threadIdx.x == 0) { tok_of[row] = t; wt_of[row] = topw[t*2 + slot]; }
  const float* xt = x + (size_t)t * H;
  u16* dst = Xg + (size_t)row * H;
  int h = threadIdx.x * 8;
  f32x4 v0 = *(const f32x4*)(xt + h);
  f32x4 v1 = *(const f32x4*)(xt + h + 4);
  u16x8 o;
  o[0]=f2bf(v0[0]); o[1]=f2bf(v0[1]); o[2]=f2bf(v0[2]); o[3]=f2bf(v0[3]);
  o[4]=f2bf(v1[0]); o[5]=f2bf(v1[1]); o[6]=f2bf(v1[2]); o[7]=f2bf(v1[3]);
  *(u16x8*)(dst + h) = o;
}

// ---------------- GEMM1: [cnt,2048] x (w1/w3)^T -> silu(g)*u -> Ag bf16 ----------------
__global__ __launch_bounds__(256) void gemm1_kernel(
    const u16* __restrict__ Xg,
    const float* __restrict__ w1, const float* __restrict__ w1s,
    const float* __restrict__ w3, const float* __restrict__ w3s,
    const int* __restrict__ counts, const int* __restrict__ base,
    u16* __restrict__ Ag) {
  const int e = blockIdx.y;
  const int cnt = counts[e];
  if (cnt == 0) return;
  const int n0 = blockIdx.x * 32;
  const int b0 = base[e];
  const int tid = threadIdx.x;
  const int lane = tid & 63;
  const int wave = tid >> 6;
  const int wm = wave >> 1, wn = wave & 1;   // waves: 2 in M x 2 in N

  __shared__ __align__(16) u16 As[128 * BK];
  __shared__ __align__(16) u16 B1s[32 * BK];
  __shared__ __align__(16) u16 B3s[32 * BK];

  for (int mt = 0; mt * 128 < cnt; ++mt) {
    f32x4 accg[4] = {};
    f32x4 accu[4] = {};
    for (int kb = 0; kb < H / BK; ++kb) {
      const int k0 = kb * BK;
      __syncthreads();
      // stage A: 128x128 bf16, XOR-swizzled
      #pragma unroll
      for (int i = 0; i < 8; ++i) {
        int chunk = tid + 256 * i;
        int r = chunk >> 4;
        int c = (chunk & 15) << 3;
        s16x8 v = *(const s16x8*)(Xg + (size_t)(b0 + mt * 128 + r) * H + k0 + c);
        int idx = (r * BK + c) ^ ((r & 7) << 3);
        *(s16x8*)(As + idx) = v;
      }
      // stage B1/B3: 32x128 fp32 -> *scale -> bf16 (BK == quant block, 1 scale/row)
      #pragma unroll
      for (int i = 0; i < 4; ++i) {
        int chunk = tid + 256 * i;
        int r = chunk >> 5;
        int c = (chunk & 31) << 2;
        size_t rowi = (size_t)e * II + n0 + r;
        float s1 = w1s[rowi * (H / BK) + kb];
        float s3 = w3s[rowi * (H / BK) + kb];
        f32x4 v1 = *(const f32x4*)(w1 + rowi * H + k0 + c);
        f32x4 v3 = *(const f32x4*)(w3 + rowi * H + k0 + c);
        int idx = (r * BK + c) ^ ((r & 7) << 3);
        u16x4 o1, o3;
        o1[0]=f2bf(v1[0]*s1); o1[1]=f2bf(v1[1]*s1); o1[2]=f2bf(v1[2]*s1); o1[3]=f2bf(v1[3]*s1);
        o3[0]=f2bf(v3[0]*s3); o3[1]=f2bf(v3[1]*s3); o3[2]=f2bf(v3[2]*s3); o3[3]=f2bf(v3[3]*s3);
        *(u16x4*)(B1s + idx) = o1;
        *(u16x4*)(B3s + idx) = o3;
      }
      __syncthreads();
      #pragma unroll
      for (int ks = 0; ks < 4; ++ks) {
        s16x8 b1, b3;
        {
          int r = wn * 16 + (lane & 15);
          int idx = (r * BK + ks * 32 + (lane >> 4) * 8) ^ ((r & 7) << 3);
          b1 = *(const s16x8*)(B1s + idx);
          b3 = *(const s16x8*)(B3s + idx);
        }
        #pragma unroll
        for (int mi = 0; mi < 4; ++mi) {
          int r = wm * 64 + mi * 16 + (lane & 15);
          int idx = (r * BK + ks * 32 + (lane >> 4) * 8) ^ ((r & 7) << 3);
          s16x8 a = *(const s16x8*)(As + idx);
          accg[mi] = __builtin_amdgcn_mfma_f32_16x16x32_bf16(a, b1, accg[mi], 0, 0, 0);
          accu[mi] = __builtin_amdgcn_mfma_f32_16x16x32_bf16(a, b3, accu[mi], 0, 0, 0);
        }
      }
    }
    // epilogue: silu(g)*u -> bf16
    const int col = n0 + wn * 16 + (lane & 15);
    #pragma unroll
    for (int mi = 0; mi < 4; ++mi) {
      #pragma unroll
      for (int r4 = 0; r4 < 4; ++r4) {
        int mrow = mt * 128 + wm * 64 + mi * 16 + ((lane >> 4) << 2) + r4;
        if (mrow < cnt) {
          float g = accg[mi][r4];
          float u = accu[mi][r4];
          float a = g / (1.f + expf(-g)) * u;
          Ag[(size_t)(b0 + mrow) * II + col] = f2bf(a);
        }
      }
    }
  }
}

// ---------------- GEMM2: [cnt,768] x w2^T -> *route_wt -> atomicAdd y ----------------
__global__ __launch_bounds__(256) void gemm2_kernel(
    const u16* __restrict__ Ag,
    const float* __restrict__ w2, const float* __restrict__ w2s,
    const int* __restrict__ counts, const int* __restrict__ base,
    const int* __restrict__ tok_of, const float* __restrict__ wt_of,
    float* __restrict__ y) {
  const int e = blockIdx.y;
  const int cnt = counts[e];
  if (cnt == 0) return;
  const int n0 = blockIdx.x * 64;
  const int b0 = base[e];
  const int tid = threadIdx.x;
  const int lane = tid & 63;
  const int wave = tid >> 6;
  const int wm = wave >> 1, wn = wave & 1;   // waves: 2 in M x 2 in N

  __shared__ __align__(16) u16 As[128 * BK];
  __shared__ __align__(16) u16 Bs[64 * BK];

  for (int mt = 0; mt * 128 < cnt; ++mt) {
    f32x4 acc[4][2] = {};
    for (int kb = 0; kb < II / BK; ++kb) {
      const int k0 = kb * BK;
      __syncthreads();
      // stage A: 128x128 bf16
      #pragma unroll
      for (int i = 0; i < 8; ++i) {
        int chunk = tid + 256 * i;
        int r = chunk >> 4;
        int c = (chunk & 15) << 3;
        s16x8 v = *(const s16x8*)(Ag + (size_t)(b0 + mt * 128 + r) * II + k0 + c);
        int idx = (r * BK + c) ^ ((r & 7) << 3);
        *(s16x8*)(As + idx) = v;
      }
      // stage B: 64x128 fp32 -> *scale -> bf16
      #pragma unroll
      for (int i = 0; i < 8; ++i) {
        int chunk = tid + 256 * i;
        int r = chunk >> 5;
        int c = (chunk & 31) << 2;
        size_t rowi = (size_t)e * H + n0 + r;
        float sc = w2s[rowi * (II / BK) + kb];
        f32x4 v = *(const f32x4*)(w2 + rowi * II + k0 + c);
        int idx = (r * BK + c) ^ ((r & 7) << 3);
        u16x4 o;
        o[0]=f2bf(v[0]*sc); o[1]=f2bf(v[1]*sc); o[2]=f2bf(v[2]*sc); o[3]=f2bf(v[3]*sc);
        *(u16x4*)(Bs + idx) = o;
      }
      __syncthreads();
      #pragma unroll
      for (int ks = 0; ks < 4; ++ks) {
        s16x8 b[2];
        #pragma unroll
        for (int ni = 0; ni < 2; ++ni) {
          int r = wn * 32 + ni * 16 + (lane & 15);
          int idx = (r * BK + ks * 32 + (lane >> 4) * 8) ^ ((r & 7) << 3);
          b[ni] = *(const s16x8*)(Bs + idx);
        }
        #pragma unroll
        for (int mi = 0; mi < 4; ++mi) {
          int r = wm * 64 + mi * 16 + (lane & 15);
          int idx = (r * BK + ks * 32 + (lane >> 4) * 8) ^ ((r & 7) << 3);
          s16x8 a = *(const s16x8*)(As + idx);
          acc[mi][0] = __builtin_amdgcn_mfma_f32_16x16x32_bf16(a, b[0], acc[mi][0], 0, 0, 0);
          acc[mi][1] = __builtin_amdgcn_mfma_f32_16x16x32_bf16(a, b[1], acc[mi][1], 0, 0, 0);
        }
      }
    }
    // epilogue: scatter-add weighted output
    #pragma unroll
    for (int mi = 0; mi < 4; ++mi) {
      int mbase = mt * 128 + wm * 64 + mi * 16 + ((lane >> 4) << 2);
      #pragma unroll
      for (int r4 = 0; r4 < 4; ++r4) {
        int mrow = mbase + r4;
        if (mrow < cnt) {
          int grow = b0 + mrow;
          int t = tok_of[grow];
          float wt = wt_of[grow];
          #pragma unroll
          for (int ni = 0; ni < 2; ++ni) {
            int hcol = n0 + wn * 32 + ni * 16 + (lane & 15);
            atomicAdd(y + (size_t)t * H + hcol, acc[mi][ni][r4] * wt);
          }
        }
      }
    }
  }
}

extern "C" void kernel_launch(void* const* d_in, const int* in_sizes, int n_in,
                              void* d_out, int out_size, void* d_ws, size_t ws_size,
                              hipStream_t stream) {
  const float* x   = (const float*)d_in[0];
  const float* gw  = (const float*)d_in[1];
  const float* w1  = (const float*)d_in[2];
  const float* w1s = (const float*)d_in[3];
  const float* w3  = (const float*)d_in[4];
  const float* w3s = (const float*)d_in[5];
  const float* w2  = (const float*)d_in[6];
  const float* w2s = (const float*)d_in[7];
  float* y = (float*)d_out;

  char* ws = (char*)d_ws;
  int*   counts = (int*)(ws + 0);            // 16 ints
  int*   basep  = (int*)(ws + 64);           // 17 ints
  int*   topi   = (int*)(ws + 256);          // 1024 ints
  float* topw   = (float*)(ws + 256 + 4096);
  int*   pos    = (int*)(ws + 256 + 8192);
  int*   tok_of = (int*)(ws + 256 + 12288);
  float* wt_of  = (float*)(ws + 256 + 16384);
  u16*   Xg     = (u16*)(ws + 256 + 20480);                       // (1024+128) x 2048 bf16
  u16*   Ag     = (u16*)(ws + 256 + 20480 + (size_t)1152*H*2);    // (1024+128) x 768 bf16

  hipMemsetAsync(counts, 0, 64, stream);
  hipMemsetAsync(y, 0, (size_t)out_size * sizeof(float), stream);

  router_kernel<<<TT, 256, 0, stream>>>(x, gw, counts, topi, topw, pos);
  prefix_kernel<<<1, 1, 0, stream>>>(counts, basep);
  gather_kernel<<<dim3(TT, 2), 256, 0, stream>>>(x, topi, topw, pos, basep, Xg, tok_of, wt_of);
  gemm1_kernel<<<dim3(II / 32, EE), 256, 0, stream>>>(Xg, w1, w1s, w3, w3s, counts, basep, Ag);
  gemm2_kernel<<<dim3(H / 64, EE), 256, 0, stream>>>(Ag, w2, w2s, counts, basep, tok_of, wt_of, y);
}

// Round 2
// 132.261 us; speedup vs baseline: 1.4914x; 1.4914x over previous
//
#include <hip/hip_runtime.h>
#include <math.h>

#define H 2048
#define II 768
#define TT 512
#define EE 16
#define BK 64

typedef float f32x4 __attribute__((ext_vector_type(4)));
typedef short s16x8 __attribute__((ext_vector_type(8)));
typedef unsigned short u16;
typedef u16 u16x8 __attribute__((ext_vector_type(8)));

__device__ __forceinline__ u16 f2bf(float f) {
  unsigned int u = __float_as_uint(f);
  u += 0x7fffu + ((u >> 16) & 1u);   // round-to-nearest-even
  return (u16)(u >> 16);
}

// ---------------- router: logits, sigmoid, top2, counts ----------------
__global__ void router_kernel(const float* __restrict__ x, const float* __restrict__ gw,
                              int* __restrict__ counts, int* __restrict__ topi,
                              float* __restrict__ topw, int* __restrict__ pos) {
  int t = blockIdx.x;
  int tid = threadIdx.x;
  int wave = tid >> 6, lane = tid & 63;
  __shared__ float logits[EE];
  const float* xt = x + (size_t)t * H;
  for (int e = wave * 4; e < wave * 4 + 4; ++e) {
    const float* ge = gw + (size_t)e * H;
    float p = 0.f;
    for (int h = lane * 4; h < H; h += 64 * 4) {
      f32x4 xv = *(const f32x4*)(xt + h);
      f32x4 gv = *(const f32x4*)(ge + h);
      p += xv[0]*gv[0] + xv[1]*gv[1] + xv[2]*gv[2] + xv[3]*gv[3];
    }
    #pragma unroll
    for (int off = 32; off > 0; off >>= 1) p += __shfl_down(p, off);
    if (lane == 0) logits[e] = p;
  }
  __syncthreads();
  if (tid == 0) {
    float s[EE];
    #pragma unroll
    for (int e = 0; e < EE; ++e) s[e] = 1.f / (1.f + expf(-logits[e]));
    int i0 = 0;
    for (int e = 1; e < EE; ++e) if (s[e] > s[i0]) i0 = e;
    int i1 = -1;
    for (int e = 0; e < EE; ++e) {
      if (e == i0) continue;
      if (i1 < 0 || s[e] > s[i1]) i1 = e;
    }
    float w0 = s[i0], w1v = s[i1];
    float inv = 1.f / (w0 + w1v);
    w0 *= inv; w1v *= inv;
    topi[t*2+0] = i0; topi[t*2+1] = i1;
    topw[t*2+0] = w0; topw[t*2+1] = w1v;
    pos[t*2+0] = atomicAdd(&counts[i0], 1);
    pos[t*2+1] = atomicAdd(&counts[i1], 1);
  }
}

// ---------------- prefix sum over 16 experts ----------------
__global__ void prefix_kernel(const int* __restrict__ counts, int* __restrict__ base) {
  int s = 0;
  for (int e = 0; e < EE; ++e) { base[e] = s; s += counts[e]; }
  base[EE] = s;
}

// ---------------- gather tokens into expert-contiguous bf16 rows ----------------
__global__ void gather_kernel(const float* __restrict__ x, const int* __restrict__ topi,
                              const float* __restrict__ topw, const int* __restrict__ pos,
                              const int* __restrict__ base, u16* __restrict__ Xg,
                              int* __restrict__ tok_of, float* __restrict__ wt_of) {
  int t = blockIdx.x, slot = blockIdx.y;
  int e = topi[t*2 + slot];
  int row = base[e] + pos[t*2 + slot];
  if (threadIdx.x == 0) { tok_of[row] = t; wt_of[row] = topw[t*2 + slot]; }
  const float* xt = x + (size_t)t * H;
  u16* dst = Xg + (size_t)row * H;
  int h = threadIdx.x * 8;
  f32x4 v0 = *(const f32x4*)(xt + h);
  f32x4 v1 = *(const f32x4*)(xt + h + 4);
  u16x8 o;
  o[0]=f2bf(v0[0]); o[1]=f2bf(v0[1]); o[2]=f2bf(v0[2]); o[3]=f2bf(v0[3]);
  o[4]=f2bf(v1[0]); o[5]=f2bf(v1[1]); o[6]=f2bf(v1[2]); o[7]=f2bf(v1[3]);
  *(u16x8*)(dst + h) = o;
}

// ---------------- GEMM1: [cnt,2048] x (w1/w3)^T -> silu(g)*u -> Ag bf16 ----------------
// BM=64, BN=16 (both w1 and w3), BK=64; grid (48, 16); 2-phase reg-staged pipeline.
__global__ __launch_bounds__(256, 4) void gemm1_kernel(
    const u16* __restrict__ Xg,
    const float* __restrict__ w1, const float* __restrict__ w1s,
    const float* __restrict__ w3, const float* __restrict__ w3s,
    const int* __restrict__ counts, const int* __restrict__ base,
    u16* __restrict__ Ag) {
  const int e = blockIdx.y;
  const int cnt = counts[e];
  if (cnt == 0) return;
  const int n0 = blockIdx.x * 16;
  const int b0 = base[e];
  const int tid = threadIdx.x;
  const int lane = tid & 63;
  const int w = tid >> 6;

  __shared__ __align__(16) u16 As[64 * 64];
  __shared__ __align__(16) u16 Bs[2][16 * 64];   // [0]=w1, [1]=w3

  // staging coords (reg-staged, XOR-swizzled both sides)
  const int rA = tid >> 3;                 // rows rA and rA+32
  const int cA = (tid & 7) << 3;
  const int cAs = cA ^ ((rA & 7) << 3);    // (rA+32)&7 == rA&7
  const int isB3 = tid >> 7;
  const int rB = (tid & 127) >> 3;         // 0..15
  const int cBs = cA ^ ((rB & 7) << 3);
  const float* wsrc = (isB3 ? w3 : w1) + (size_t)(e * II + n0 + rB) * H + cA;
  const float* ssrc = (isB3 ? w3s : w1s) + (size_t)(e * II + n0 + rB) * (H / 128);
  u16* bdst = &Bs[isB3][rB * 64 + cBs];

  // compute coords
  const int arow = w * 16 + (lane & 15);
  const int acol0 = (lane >> 4) << 3;
  const int brow = lane & 15;
  const int aswz = (arow & 7) << 3;
  const int bswz = (brow & 7) << 3;

  const int nmt = (cnt + 63) >> 6;
  for (int mt = 0; mt < nmt; ++mt) {
    const u16* asrc = Xg + (size_t)(b0 + mt * 64 + rA) * H + cA;
    f32x4 accg = {}, accu = {};
    s16x8 a0, a1; f32x4 bv0, bv1; float sc;
    // prologue: load+store tile 0
    a0 = *(const s16x8*)(asrc);
    a1 = *(const s16x8*)(asrc + (size_t)32 * H);
    bv0 = *(const f32x4*)(wsrc);
    bv1 = *(const f32x4*)(wsrc + 4);
    sc = ssrc[0];
    {
      *(s16x8*)(As + rA * 64 + cAs) = a0;
      *(s16x8*)(As + (rA + 32) * 64 + cAs) = a1;
      u16x8 ob;
      ob[0]=f2bf(bv0[0]*sc); ob[1]=f2bf(bv0[1]*sc); ob[2]=f2bf(bv0[2]*sc); ob[3]=f2bf(bv0[3]*sc);
      ob[4]=f2bf(bv1[0]*sc); ob[5]=f2bf(bv1[1]*sc); ob[6]=f2bf(bv1[2]*sc); ob[7]=f2bf(bv1[3]*sc);
      *(u16x8*)bdst = ob;
    }
    __syncthreads();
    for (int t = 0; t < H / BK; ++t) {
      const bool notlast = (t + 1 < H / BK);
      if (notlast) {   // issue next tile's loads BEFORE compute (T14)
        const int k1 = (t + 1) * BK;
        a0 = *(const s16x8*)(asrc + k1);
        a1 = *(const s16x8*)(asrc + (size_t)32 * H + k1);
        bv0 = *(const f32x4*)(wsrc + k1);
        bv1 = *(const f32x4*)(wsrc + k1 + 4);
        sc = ssrc[k1 >> 7];
      }
      #pragma unroll
      for (int ks = 0; ks < 2; ++ks) {
        const int ac = ks * 32 + acol0;
        s16x8 af  = *(const s16x8*)(As + arow * 64 + (ac ^ aswz));
        const int bix = brow * 64 + (ac ^ bswz);
        s16x8 b1f = *(const s16x8*)(Bs[0] + bix);
        s16x8 b3f = *(const s16x8*)(Bs[1] + bix);
        accg = __builtin_amdgcn_mfma_f32_16x16x32_bf16(af, b1f, accg, 0, 0, 0);
        accu = __builtin_amdgcn_mfma_f32_16x16x32_bf16(af, b3f, accu, 0, 0, 0);
      }
      __syncthreads();
      if (notlast) {   // convert + LDS write after barrier (vmcnt waits here)
        *(s16x8*)(As + rA * 64 + cAs) = a0;
        *(s16x8*)(As + (rA + 32) * 64 + cAs) = a1;
        u16x8 ob;
        ob[0]=f2bf(bv0[0]*sc); ob[1]=f2bf(bv0[1]*sc); ob[2]=f2bf(bv0[2]*sc); ob[3]=f2bf(bv0[3]*sc);
        ob[4]=f2bf(bv1[0]*sc); ob[5]=f2bf(bv1[1]*sc); ob[6]=f2bf(bv1[2]*sc); ob[7]=f2bf(bv1[3]*sc);
        *(u16x8*)bdst = ob;
      }
      __syncthreads();
    }
    // epilogue: fused silu(g)*u -> bf16
    const int col = n0 + (lane & 15);
    #pragma unroll
    for (int r4 = 0; r4 < 4; ++r4) {
      int mrow = mt * 64 + w * 16 + ((lane >> 4) << 2) + r4;
      if (mrow < cnt) {
        float g = accg[r4], u = accu[r4];
        float a = g / (1.f + expf(-g)) * u;
        Ag[(size_t)(b0 + mrow) * II + col] = f2bf(a);
      }
    }
  }
}

// ---------------- GEMM2: [cnt,768] x w2^T -> *route_wt -> atomicAdd y ----------------
// BM=64, BN=32, BK=64; grid (64, 16); 2-phase reg-staged pipeline.
__global__ __launch_bounds__(256, 4) void gemm2_kernel(
    const u16* __restrict__ Ag,
    const float* __restrict__ w2, const float* __restrict__ w2s,
    const int* __restrict__ counts, const int* __restrict__ base,
    const int* __restrict__ tok_of, const float* __restrict__ wt_of,
    float* __restrict__ y) {
  const int e = blockIdx.y;
  const int cnt = counts[e];
  if (cnt == 0) return;
  const int n0 = blockIdx.x * 32;
  const int b0 = base[e];
  const int tid = threadIdx.x;
  const int lane = tid & 63;
  const int w = tid >> 6;

  __shared__ __align__(16) u16 As[64 * 64];
  __shared__ __align__(16) u16 Bs[32 * 64];

  const int rA = tid >> 3;                 // rows rA and rA+32
  const int cA = (tid & 7) << 3;
  const int cAs = cA ^ ((rA & 7) << 3);
  const int rB = tid >> 3;                 // 0..31
  const int cBs = cA ^ ((rB & 7) << 3);
  const float* wsrc = w2 + (size_t)(e * H + n0 + rB) * II + cA;
  const float* ssrc = w2s + (size_t)(e * H + n0 + rB) * (II / 128);
  u16* bdst = &Bs[rB * 64 + cBs];

  const int arow = w * 16 + (lane & 15);
  const int acol0 = (lane >> 4) << 3;
  const int brow = lane & 15;
  const int aswz = (arow & 7) << 3;

  const int nmt = (cnt + 63) >> 6;
  for (int mt = 0; mt < nmt; ++mt) {
    const u16* asrc = Ag + (size_t)(b0 + mt * 64 + rA) * II + cA;
    f32x4 acc0 = {}, acc1 = {};
    s16x8 a0, a1; f32x4 bv0, bv1; float sc;
    a0 = *(const s16x8*)(asrc);
    a1 = *(const s16x8*)(asrc + (size_t)32 * II);
    bv0 = *(const f32x4*)(wsrc);
    bv1 = *(const f32x4*)(wsrc + 4);
    sc = ssrc[0];
    {
      *(s16x8*)(As + rA * 64 + cAs) = a0;
      *(s16x8*)(As + (rA + 32) * 64 + cAs) = a1;
      u16x8 ob;
      ob[0]=f2bf(bv0[0]*sc); ob[1]=f2bf(bv0[1]*sc); ob[2]=f2bf(bv0[2]*sc); ob[3]=f2bf(bv0[3]*sc);
      ob[4]=f2bf(bv1[0]*sc); ob[5]=f2bf(bv1[1]*sc); ob[6]=f2bf(bv1[2]*sc); ob[7]=f2bf(bv1[3]*sc);
      *(u16x8*)bdst = ob;
    }
    __syncthreads();
    for (int t = 0; t < II / BK; ++t) {
      const bool notlast = (t + 1 < II / BK);
      if (notlast) {
        const int k1 = (t + 1) * BK;
        a0 = *(const s16x8*)(asrc + k1);
        a1 = *(const s16x8*)(asrc + (size_t)32 * II + k1);
        bv0 = *(const f32x4*)(wsrc + k1);
        bv1 = *(const f32x4*)(wsrc + k1 + 4);
        sc = ssrc[k1 >> 7];
      }
      #pragma unroll
      for (int ks = 0; ks < 2; ++ks) {
        const int ac = ks * 32 + acol0;
        s16x8 af  = *(const s16x8*)(As + arow * 64 + (ac ^ aswz));
        s16x8 b0f = *(const s16x8*)(Bs + brow * 64 + (ac ^ ((brow & 7) << 3)));
        const int br1 = brow + 16;
        s16x8 b1f = *(const s16x8*)(Bs + br1 * 64 + (ac ^ ((br1 & 7) << 3)));
        acc0 = __builtin_amdgcn_mfma_f32_16x16x32_bf16(af, b0f, acc0, 0, 0, 0);
        acc1 = __builtin_amdgcn_mfma_f32_16x16x32_bf16(af, b1f, acc1, 0, 0, 0);
      }
      __syncthreads();
      if (notlast) {
        *(s16x8*)(As + rA * 64 + cAs) = a0;
        *(s16x8*)(As + (rA + 32) * 64 + cAs) = a1;
        u16x8 ob;
        ob[0]=f2bf(bv0[0]*sc); ob[1]=f2bf(bv0[1]*sc); ob[2]=f2bf(bv0[2]*sc); ob[3]=f2bf(bv0[3]*sc);
        ob[4]=f2bf(bv1[0]*sc); ob[5]=f2bf(bv1[1]*sc); ob[6]=f2bf(bv1[2]*sc); ob[7]=f2bf(bv1[3]*sc);
        *(u16x8*)bdst = ob;
      }
      __syncthreads();
    }
    // epilogue: scatter-add weighted output
    #pragma unroll
    for (int r4 = 0; r4 < 4; ++r4) {
      int mrow = mt * 64 + w * 16 + ((lane >> 4) << 2) + r4;
      if (mrow < cnt) {
        int grow = b0 + mrow;
        int t = tok_of[grow];
        float wt = wt_of[grow];
        atomicAdd(y + (size_t)t * H + n0 + (lane & 15), acc0[r4] * wt);
        atomicAdd(y + (size_t)t * H + n0 + 16 + (lane & 15), acc1[r4] * wt);
      }
    }
  }
}

extern "C" void kernel_launch(void* const* d_in, const int* in_sizes, int n_in,
                              void* d_out, int out_size, void* d_ws, size_t ws_size,
                              hipStream_t stream) {
  const float* x   = (const float*)d_in[0];
  const float* gw  = (const float*)d_in[1];
  const float* w1  = (const float*)d_in[2];
  const float* w1s = (const float*)d_in[3];
  const float* w3  = (const float*)d_in[4];
  const float* w3s = (const float*)d_in[5];
  const float* w2  = (const float*)d_in[6];
  const float* w2s = (const float*)d_in[7];
  float* y = (float*)d_out;

  char* ws = (char*)d_ws;
  int*   counts = (int*)(ws + 0);            // 16 ints
  int*   basep  = (int*)(ws + 64);           // 17 ints
  int*   topi   = (int*)(ws + 256);          // 1024 ints
  float* topw   = (float*)(ws + 256 + 4096);
  int*   pos    = (int*)(ws + 256 + 8192);
  int*   tok_of = (int*)(ws + 256 + 12288);
  float* wt_of  = (float*)(ws + 256 + 16384);
  u16*   Xg     = (u16*)(ws + 256 + 20480);                       // (1024+128) x 2048 bf16
  u16*   Ag     = (u16*)(ws + 256 + 20480 + (size_t)1152*H*2);    // (1024+128) x 768 bf16

  hipMemsetAsync(counts, 0, 64, stream);
  hipMemsetAsync(y, 0, (size_t)out_size * sizeof(float), stream);

  router_kernel<<<TT, 256, 0, stream>>>(x, gw, counts, topi, topw, pos);
  prefix_kernel<<<1, 1, 0, stream>>>(counts, basep);
  gather_kernel<<<dim3(TT, 2), 256, 0, stream>>>(x, topi, topw, pos, basep, Xg, tok_of, wt_of);
  gemm1_kernel<<<dim3(II / 16, EE), 256, 0, stream>>>(Xg, w1, w1s, w3, w3s, counts, basep, Ag);
  gemm2_kernel<<<dim3(H / 32, EE), 256, 0, stream>>>(Ag, w2, w2s, counts, basep, tok_of, wt_of, y);
}